// Round 4
// baseline (3504.635 us; speedup 1.0000x reference)
//
#include <hip/hip_runtime.h>
#include <hip/hip_bf16.h>

#define B_ 32
#define S_ 512
#define IN_ 300
#define H_ 180
#define G4_ 720
#define OUT_ 60
#define R_ 16384
#define TC_ 32
#define NC_ 16

// packed-weight region word offsets (wfu = uint/float view of same region)
#define BFRAG_O 0u        // uints [4 layers][12 w][4 g][6 s][64 lane][4 wd] f16-pair Whh B-frags = 294,912
#define PW0_O   294912u   // uints [720][150] f16-pair Wih0 = 108,000
#define PWR_O   402912u   // uints [3][720][90] f16-pair WihR = 194,400
#define BIASF_O 597312u   // fp32 [4][720] (bih+bhh) = 2,880
#define LINWF_O 600192u   // fp32 [60][180] = 10,800
#define LINBF_O 610992u   // fp32 [60]
#define WFT_    611052u

// ws float offsets (total 9,530,605 fl = 38.1 MB; ws >= 40 MB measured)
#define XG_O   0u         // [4 layers][2 ring] fragment-layout xg = 8 x 786,432
#define HR_O   6291456u   // [3 layers][2 ring][1024][180] fp32 = 1,105,920
#define H3_O   7397376u   // bf16 [16384][180] = 1,474,560 fl
#define WFU_O  8871936u   // 611,052 fl
#define STH_O  9482988u   // [4][32][180] h state
#define STC_O  9506028u   // [4][2 half][12 w][64 lane] float4 c state = 24,576
#define FLAG_O 9530604u
#define XGSLOT 786432
#define HRSLOT 184320

#if defined(__has_builtin)
#if __has_builtin(__builtin_amdgcn_fdot2)
#define HAVE_FDOT2 1
#endif
#endif

typedef _Float16 f16x2 __attribute__((ext_vector_type(2)));
typedef _Float16 f16x8 __attribute__((ext_vector_type(8)));
typedef float f32x4 __attribute__((ext_vector_type(4)));

union U16x8 { uint4 u; f16x8 h; };

struct Plan {
  int nl; int ll[4]; int lc[4];
  int ng; int gl[4]; int gc[4];
};

__device__ __forceinline__ float sigf(float x)   { return 1.f / (1.f + __expf(-x)); }
__device__ __forceinline__ float tanhf2(float x) { return 2.f / (1.f + __expf(-2.f * x)) - 1.f; }
__device__ __forceinline__ float toF(__hip_bfloat16 x) { return __bfloat162float(x); }
__device__ __forceinline__ float ldr(const void* p, long i, int fl) {
  return fl ? ((const float*)p)[i] : toF(((const __hip_bfloat16*)p)[i]);
}
__device__ __forceinline__ unsigned f16b(_Float16 h) {
  union { _Float16 f; unsigned short s; } x; x.f = h; return x.s;
}
__device__ __forceinline__ float h2f(unsigned s) {
  union { unsigned short s; _Float16 f; } x; x.s = (unsigned short)(s & 0xFFFFu);
  return (float)x.f;
}
__device__ __forceinline__ f16x2 u2h(unsigned u) {
  union { unsigned u; f16x2 v; } x; x.u = u; return x.v;
}
__device__ __forceinline__ float fd2(unsigned hu, unsigned wu, float acc) {
#ifdef HAVE_FDOT2
  return __builtin_amdgcn_fdot2(u2h(hu), u2h(wu), acc, false);
#else
  return acc + h2f(hu) * h2f(wu) + h2f(hu >> 16) * h2f(wu >> 16);
#endif
}
__device__ __forceinline__ unsigned packpair_f32(float lo, float hi) {
  return f16b((_Float16)lo) | (f16b((_Float16)hi) << 16);
}
__device__ __forceinline__ unsigned packpair_bf16(unsigned u) {
  union { unsigned v; float f; } a, b;
  a.v = u << 16; b.v = u & 0xFFFF0000u;
  return packpair_f32(a.f, b.f);
}

// 24 pinned B fragments (4 gates x 6 k-steps), f16x8 each (4 AGPRs).
// "a" constraint: keep Whh OUT of the arch-VGPR class -> no scratch spill;
// gfx950 MFMA reads A/B directly from AGPRs (unified file, AV operand class).
// NOTE: load-time single-operand pins ONLY — a combined in-loop pin with 24
// tied operands exceeds the allocator's recoloring depth (round-3 failure).
#define REPGS(M) \
  M(0,0) M(0,1) M(0,2) M(0,3) M(0,4) M(0,5) \
  M(1,0) M(1,1) M(1,2) M(1,3) M(1,4) M(1,5) \
  M(2,0) M(2,1) M(2,2) M(2,3) M(2,4) M(2,5) \
  M(3,0) M(3,1) M(3,2) M(3,3) M(3,4) M(3,5)

#define LBF(g,s) \
  U16x8 ub##g##_##s; ub##g##_##s.u = bfp[((g) * 6 + (s)) * 64]; \
  f16x8 B##g##_##s = ub##g##_##s.h; \
  asm volatile("" : "+a"(B##g##_##s));

// one k-step: A frag from swizzled LDS, 4 gate MFMAs (in-place acc)
#define MST(s) { \
  const f16x8 av = *(const f16x8*)(hbc + (li * 384 + (((q * 16) + (s) * 64) ^ ((li & 7) << 4)))); \
  a0 = __builtin_amdgcn_mfma_f32_16x16x32_f16(av, B0_##s, a0, 0, 0, 0); \
  a1 = __builtin_amdgcn_mfma_f32_16x16x32_f16(av, B1_##s, a1, 0, 0, 0); \
  a2 = __builtin_amdgcn_mfma_f32_16x16x32_f16(av, B2_##s, a2, 0, 0, 0); \
  a3 = __builtin_amdgcn_mfma_f32_16x16x32_f16(av, B3_##s, a3, 0, 0, 0); }

// ---------------------------------------------------------------------------
__global__ __launch_bounds__(256) void detect_kernel(
    const unsigned short* __restrict__ xw, int* __restrict__ flag) {
  __shared__ int cnt;
  if (threadIdx.x == 0) cnt = 0;
  __syncthreads();
  int lc = 0;
  for (int i = threadIdx.x; i < 2048; i += 256) {
    const int e = (xw[i] >> 7) & 0xFF;
    if (e >= 0xC0 || (e > 0 && e < 0x40)) lc++;
  }
  atomicAdd(&cnt, lc);
  __syncthreads();
  if (threadIdx.x == 0) *flag = (cnt > 100) ? 1 : 0;
}

// ---------------------------------------------------------------------------
// prep: Whh as MFMA B-fragments; Wih0 packed [o][150]; WihR packed [l][o][90];
// bias/linw/linb fp32.
// ---------------------------------------------------------------------------
__global__ __launch_bounds__(256) void prep_kernel(
    const void* __restrict__ wih0, const void* __restrict__ wihr,
    const void* __restrict__ whh,  const void* __restrict__ bih,
    const void* __restrict__ bhh,  const void* __restrict__ linw,
    const void* __restrict__ linb, float* __restrict__ wf,
    const int* __restrict__ flag) {
  const unsigned i = blockIdx.x * 256u + threadIdx.x;
  if (i >= WFT_) return;
  const int fl = *flag;
  if (i < PW0_O) {            // Whh B-fragments: word = [l][w][g][s][lane][wd]
    const unsigned l = i / 73728u, idx = i % 73728u;
    const unsigned wd = idx & 3u, lane = (idx >> 2) & 63u;
    const unsigned rest = idx >> 8;
    const unsigned s = rest % 6u, gq = rest / 6u;
    const unsigned g = gq & 3u, wv = gq >> 2;
    const unsigned k0 = s * 32u + ((lane >> 4) << 3) + wd * 2u;  // k index (pair base)
    const unsigned uu = wv * 16u + (lane & 15u);                 // unit (col)
    float v0 = 0.f, v1 = 0.f;
    if (uu < 180u) {
      const long b = (long)l * 129600 + (long)(g * 180u + uu) * H_;
      if (k0 < 180u)      v0 = ldr(whh, b + k0, fl);
      if (k0 + 1u < 180u) v1 = ldr(whh, b + k0 + 1u, fl);
    }
    ((unsigned*)wf)[i] = packpair_f32(v0, v1);
    return;
  }
  if (i < PWR_O) {            // Wih0 [o][150] pairs
    const unsigned j = i - PW0_O, o = j / 150u, kp = j % 150u;
    const long b = (long)o * IN_;
    ((unsigned*)wf)[i] =
        packpair_f32(ldr(wih0, b + 2 * kp, fl), ldr(wih0, b + 2 * kp + 1, fl));
    return;
  }
  if (i < BIASF_O) {          // WihR [l][o][90] pairs
    const unsigned j = i - PWR_O, l = j / 64800u, r = j % 64800u;
    const unsigned o = r / 90u, kp = r % 90u;
    const long b = (long)l * 129600 + (long)o * H_;
    ((unsigned*)wf)[i] =
        packpair_f32(ldr(wihr, b + 2 * kp, fl), ldr(wihr, b + 2 * kp + 1, fl));
    return;
  }
  float v;
  if (i < LINWF_O)      { const unsigned j = i - BIASF_O; v = ldr(bih, j, fl) + ldr(bhh, j, fl); }
  else if (i < LINBF_O) v = ldr(linw, i - LINWF_O, fl);
  else                  v = ldr(linb, i - LINBF_O, fl);
  wf[i] = v;
}

// ---------------------------------------------------------------------------
// fused: blocks [0, nl*2) = LSTM jobs (MFMA recurrence, 16 batches/block,
// 12 waves: wave w owns units [16w,16w+16) x all 4 gates -> in-lane c/h update,
// one raw barrier per step, no vmcnt drain); rest = barrier GEMM (f16 dot2,
// proven tiling) writing xg in MFMA C-fragment layout.
// ---------------------------------------------------------------------------
__global__ __launch_bounds__(768, 3) void fused_kernel(
    const void* __restrict__ x, const int* __restrict__ flag,
    const unsigned* __restrict__ wfu,
    float* __restrict__ xg, float* __restrict__ hr,
    __hip_bfloat16* __restrict__ h3,
    float* __restrict__ sth, float* __restrict__ stc, Plan p) {
  __shared__ __align__(16) unsigned short hbf[2 * 16 * 192];   // h dbuf, XOR-swizzled
  __shared__ __align__(16) unsigned Asu[3][10][68];
  __shared__ __align__(16) unsigned Bsu[3][10][68];

  const int bid = blockIdx.x;
  if (bid < p.nl * 2) {
    // ---------------- LSTM: MFMA recurrence ----------------
    const int j = bid >> 1, half = bid & 1;
    const int l = p.ll[j], c = p.lc[j];
    const int tid = threadIdx.x;
    const int w = tid >> 6, lane = tid & 63;
    const int li = lane & 15, q = lane >> 4;
    const int u = w * 16 + li;                       // unit (0..191, pad >=180)
    const uint4* bfp = (const uint4*)(wfu + BFRAG_O) +
                       ((long)l * 18432 + w * 1536 + lane);
    REPGS(LBF)
    f32x4* stc4 = (f32x4*)stc;
    const int sidx = ((l * 2 + half) * 12 + w) * 64 + lane;
    f32x4 cr = {0.f, 0.f, 0.f, 0.f};
    if (c != 0) cr = stc4[sidx];
    float* hrs = (l < 3) ? (hr + (long)(l * 2 + (c & 1)) * HRSLOT) : (float*)0;
    const f32x4* xgf = (const f32x4*)(xg + (long)(l * 2 + (c & 1)) * XGSLOT);
    const int xb = (half * 12 + w) * 256 + lane;
    // seed h buffer 0 from carried state (zeros on first chunk / pad cols)
    {
      char* hbw0 = (char*)hbf;
      for (int e = tid; e < 16 * 192; e += 768) {
        const int bb = e / 192, uu = e - bb * 192;
        float hv = 0.f;
        if (c != 0 && uu < 180) hv = sth[(l * 32 + half * 16 + bb) * 180 + uu];
        *(unsigned short*)(hbw0 + bb * 384 + ((uu * 2) ^ ((bb & 7) << 4))) =
            (unsigned short)f16b((_Float16)hv);
      }
    }
    f32x4 nx0 = xgf[xb], nx1 = xgf[xb + 64], nx2 = xgf[xb + 128], nx3 = xgf[xb + 192];
    __syncthreads();
#pragma unroll 1
    for (int t = 0; t < TC_; ++t) {
      const char* hbc = (const char*)hbf + ((t & 1) ? 6144 : 0);
      char* hbw = (char*)hbf + ((t & 1) ? 0 : 6144);
      f32x4 a0 = nx0, a1 = nx1, a2 = nx2, a3 = nx3;   // acc init = xg (bias folded)
      MST(0) MST(1) MST(2) MST(3) MST(4) MST(5)
      if (t + 1 < TC_) {                               // prefetch next xg fragment
        const long xi = xb + (long)(t + 1) * 6144;
        nx0 = xgf[xi]; nx1 = xgf[xi + 64]; nx2 = xgf[xi + 128]; nx3 = xgf[xi + 192];
      }
#pragma unroll
      for (int r = 0; r < 4; ++r) {
        const float ig = sigf(a0[r]), fg = sigf(a1[r]);
        const float gg = tanhf2(a2[r]), og = sigf(a3[r]);
        const float cn = fg * cr[r] + ig * gg;
        cr[r] = cn;
        float h = og * tanhf2(cn);
        if (u >= 180) h = 0.f;                         // keep pad cols clean
        const int brow = q * 4 + r;
        *(unsigned short*)(hbw + brow * 384 + ((u * 2) ^ ((brow & 7) << 4))) =
            (unsigned short)f16b((_Float16)h);
        if (u < 180) {
          const int b = half * 16 + brow;
          if (l < 3) hrs[(long)(b * TC_ + t) * H_ + u] = h;
          else       h3[((long)b * S_ + c * TC_ + t) * H_ + u] = __float2bfloat16(h);
          if (t == TC_ - 1) sth[(l * 32 + b) * H_ + u] = h;
        }
      }
      // raw barrier: LDS writes visible, global stores/prefetch stay in flight
      asm volatile("s_waitcnt lgkmcnt(0)\n\ts_barrier" ::: "memory");
    }
    stc4[sidx] = cr;
    return;
  }

  // ---------------- GEMM: f16-pair dot2, proven barrier tiling ----------
  const int gb = bid - p.nl * 2;
  const int g = threadIdx.x >> 8, t = threadIdx.x & 255;
  const int ti = gb * 3 + g;              // grid sized exactly: ti < ng*192
  const int jj = ti / 192, idx = ti % 192;
  const int rt = idx & 15, ct = idx >> 4;
  const int l = p.gl[jj], c = p.gc[jj];
  const int fl = *flag;
  const int KP = (l == 0) ? 150 : 90;     // k-pairs
  const unsigned* Wp = (l == 0) ? (wfu + PW0_O)
                                : (wfu + PWR_O + (unsigned)(l - 1) * 64800u);
  const float* bias = (const float*)wfu + BIASF_O + (unsigned)l * G4_;
  const float* hA = (l == 0) ? (const float*)0
                  : hr + (long)((l - 1) * 2 + (c & 1)) * HRSLOT;
  float* dst = xg + (long)(l * 2 + (c & 1)) * XGSLOT;
  const int rho0 = rt * 64, o0 = ct * 64;
  const int tx = t & 15, ty = t >> 4;
  float acc[4][4] = {};
  for (int kp0 = 0; kp0 < KP; kp0 += 10) {
    for (int e = t; e < 640; e += 256) {
      const int rl = e / 10, pp = e % 10;
      const int rho = rho0 + rl;
      unsigned av;
      if (l == 0) {
        const int bb = rho >> 5, tl = rho & 31;
        const long gr = (long)bb * S_ + c * TC_ + tl;
        if (fl == 0) av = packpair_bf16(((const unsigned*)x)[gr * 150 + kp0 + pp]);
        else { const float2 f = ((const float2*)x)[gr * 150 + kp0 + pp];
               av = packpair_f32(f.x, f.y); }
      } else {
        const float2 f = ((const float2*)hA)[(long)rho * 90 + kp0 + pp];
        av = packpair_f32(f.x, f.y);
      }
      Asu[g][pp][rl] = av;
      const int o = o0 + rl;
      Bsu[g][pp][rl] = (o < G4_) ? Wp[(long)o * KP + kp0 + pp] : 0u;
    }
    __syncthreads();
#pragma unroll
    for (int pp = 0; pp < 10; ++pp) {
      const uint4 a4 = *(const uint4*)&Asu[g][pp][ty * 4];
      const uint4 b4 = *(const uint4*)&Bsu[g][pp][tx * 4];
      const unsigned av[4] = {a4.x, a4.y, a4.z, a4.w};
      const unsigned bv[4] = {b4.x, b4.y, b4.z, b4.w};
#pragma unroll
      for (int i = 0; i < 4; ++i)
#pragma unroll
        for (int j2 = 0; j2 < 4; ++j2) acc[i][j2] = fd2(av[i], bv[j2], acc[i][j2]);
    }
    __syncthreads();
  }
  // epilogue: write xg in LSTM MFMA C-fragment layout
  int oidx[4], ocol[4];
#pragma unroll
  for (int j2 = 0; j2 < 4; ++j2) {
    const int o = o0 + tx * 4 + j2;
    ocol[j2] = o;
    if (o < G4_) {
      const int gi = o / 180, uu = o - gi * 180;
      oidx[j2] = (uu >> 4) * 1024 + gi * 256 + (uu & 15) * 4;
    } else oidx[j2] = -1;
  }
#pragma unroll
  for (int i = 0; i < 4; ++i) {
    const int rho = rho0 + ty * 4 + i;
    const int bb = rho >> 5, tt = rho & 31;
    const int hf = bb >> 4, bt = bb & 15;
    const long rowoff = (long)(tt * 2 + hf) * 12288 + (bt >> 2) * 64 + (bt & 3);
#pragma unroll
    for (int j2 = 0; j2 < 4; ++j2)
      if (oidx[j2] >= 0) dst[rowoff + oidx[j2]] = acc[i][j2] + bias[ocol[j2]];
  }
}

// ---------------------------------------------------------------------------
// linear as tiled GEMM: [16384 x 180] @ [180 x 60] -> out[b][c][s].
// ---------------------------------------------------------------------------
__global__ __launch_bounds__(256) void linear_kernel(
    const __hip_bfloat16* __restrict__ h, const float* __restrict__ linw,
    const float* __restrict__ linb, float* __restrict__ out) {
  __shared__ __align__(16) float Ast[20][68];
  __shared__ __align__(16) float Bst[20][68];
  const int bt = blockIdx.x;
  const int b = bt >> 3, st0 = (bt & 7) * 64;
  const int t = threadIdx.x, tx = t & 15, ty = t >> 4;
  float acc[4][4] = {};
  for (int k0 = 0; k0 < H_; k0 += 20) {
    for (int e = t; e < 1280; e += 256) {
      const int rl = e / 20, kk = e % 20;
      Ast[kk][rl] = toF(h[(long)(b * S_ + st0 + rl) * H_ + k0 + kk]);
      Bst[kk][rl] = (rl < OUT_) ? linw[rl * H_ + k0 + kk] : 0.f;
    }
    __syncthreads();
#pragma unroll
    for (int kk = 0; kk < 20; ++kk) {
      const float4 a4 = *(const float4*)&Ast[kk][ty * 4];
      const float4 b4 = *(const float4*)&Bst[kk][tx * 4];
      const float av[4] = {a4.x, a4.y, a4.z, a4.w};
      const float bv[4] = {b4.x, b4.y, b4.z, b4.w};
#pragma unroll
      for (int i = 0; i < 4; ++i)
#pragma unroll
        for (int j2 = 0; j2 < 4; ++j2) acc[i][j2] += av[i] * bv[j2];
    }
    __syncthreads();
  }
#pragma unroll
  for (int i = 0; i < 4; ++i) {
    const int s = st0 + ty * 4 + i;
#pragma unroll
    for (int j2 = 0; j2 < 4; ++j2) {
      const int c = tx * 4 + j2;
      if (c < OUT_) out[((long)b * OUT_ + c) * S_ + s] = acc[i][j2] + linb[c];
    }
  }
}

// ---------------------------------------------------------------------------
__global__ __launch_bounds__(256) void mel_kernel(
    const float* __restrict__ in, float* __restrict__ out,
    const void* __restrict__ mw, const void* __restrict__ mb,
    int l, const int* __restrict__ flag) {
  const int fl = *flag;
  const int idx = blockIdx.x;
  const int s = (idx & 1) * 256 + threadIdx.x;
  const int c = (idx >> 1) % OUT_;
  const int b = idx / (2 * OUT_);
  const int j = c % 3, i = c / 3;
  float acc = ldr(mb, (l * 3 + j) * 20 + i, fl);
  const long wbase = (long)((l * 3 + j) * 20 + i) * 15;
#pragma unroll
  for (int q = 0; q < 3; ++q) {
    const int ch = 3 * i + q + j - 1;
    if (ch < 0 || ch >= OUT_) continue;
    const float* xr = in + ((long)b * OUT_ + ch) * S_;
#pragma unroll
    for (int k = 0; k < 5; ++k) {
      const int sp = s + k - 2;
      if (sp < 0 || sp >= S_) continue;
      acc += ldr(mw, wbase + q * 5 + k, fl) * xr[sp];
    }
  }
  out[((long)b * OUT_ + c) * S_ + s] = acc + in[((long)b * OUT_ + c) * S_ + s];
}

// ---------------------------------------------------------------------------
__global__ __launch_bounds__(256) void res_kernel(
    const float* __restrict__ lin, const float* __restrict__ mel,
    const void* __restrict__ rw, const void* __restrict__ rb,
    void* __restrict__ outp, const int* __restrict__ flag) {
  const int fl = *flag;
  const int q = threadIdx.x >> 6, lane = threadIdx.x & 63;
  const int bs = blockIdx.x * 4 + q;
  const int b = bs / S_, s = bs % S_;
  if (lane >= OUT_) return;
  const int c = lane;
  float acc = ldr(rb, c, fl);
  const float* x0 = lin + ((long)b * OUT_ + c) * S_;
  const float* x1 = mel + ((long)b * OUT_ + c) * S_;
#pragma unroll
  for (int k = 0; k < 5; ++k) {
    const int sp = s + k - 2;
    if (sp < 0 || sp >= S_) continue;
    acc += ldr(rw, c * 10 + k, fl) * x0[sp] + ldr(rw, c * 10 + 5 + k, fl) * x1[sp];
  }
  const long oi = (long)bs * OUT_ + c;
  if (fl == 0) ((__hip_bfloat16*)outp)[oi] = __float2bfloat16(acc);
  else ((float*)outp)[oi] = acc;
}

// ---------------------------------------------------------------------------
extern "C" void kernel_launch(void* const* d_in, const int* in_sizes, int n_in,
                              void* d_out, int out_size, void* d_ws, size_t ws_size,
                              hipStream_t stream) {
  const void* x    = d_in[0];
  const void* wih0 = d_in[1];
  const void* wihr = d_in[2];
  const void* whh  = d_in[3];
  const void* bih  = d_in[4];
  const void* bhh  = d_in[5];
  const void* linw = d_in[6];
  const void* linb = d_in[7];
  const void* melw = d_in[8];
  const void* melb = d_in[9];
  const void* resw = d_in[10];
  const void* resb = d_in[11];

  float* ws = (float*)d_ws;
  float* xg = ws + XG_O;
  float* hrp = ws + HR_O;
  __hip_bfloat16* h3 = (__hip_bfloat16*)(ws + H3_O);
  float* wf = ws + WFU_O;
  const unsigned* wfu = (const unsigned*)wf;
  float* sth = ws + STH_O;
  float* stc = ws + STC_O;
  int* flag = (int*)(ws + FLAG_O);
  float* lin = ws + XG_O;            // epilogue aliases dead xg region
  float* m1 = lin + 983040;
  float* m2 = m1 + 983040;

  detect_kernel<<<1, 256, 0, stream>>>((const unsigned short*)x, flag);
  prep_kernel<<<(WFT_ + 255) / 256, 256, 0, stream>>>(
      wih0, wihr, whh, bih, bhh, linw, linb, wf, flag);

  // prologue: gemm(0,0) only
  {
    Plan p = {};
    p.nl = 0; p.ng = 1; p.gl[0] = 0; p.gc[0] = 0;
    fused_kernel<<<64, 768, 0, stream>>>(x, flag, wfu, xg, hrp, h3, sth, stc, p);
  }
  // pipeline: lstm(l,c) at launch n = c + 2l; gemm(l,c) at n = c + 2l - 1
  for (int n = 0; n <= 21; ++n) {
    Plan p = {};
    for (int l = 0; l < 4; ++l) {
      const int c = n - 2 * l;
      if (c >= 0 && c < NC_) { p.ll[p.nl] = l; p.lc[p.nl] = c; p.nl++; }
    }
    for (int l = 0; l < 4; ++l) {
      const int c = n + 1 - 2 * l;
      if (c >= 0 && c < NC_) { p.gl[p.ng] = l; p.gc[p.ng] = c; p.ng++; }
    }
    const int grid = p.nl * 2 + p.ng * 64;
    fused_kernel<<<grid, 768, 0, stream>>>(x, flag, wfu, xg, hrp, h3, sth, stc, p);
  }

  linear_kernel<<<256, 256, 0, stream>>>(h3, wf + LINWF_O, wf + LINBF_O, lin);
  mel_kernel<<<B_ * OUT_ * 2, 256, 0, stream>>>(lin, m1, melw, melb, 0, flag);
  mel_kernel<<<B_ * OUT_ * 2, 256, 0, stream>>>(m1, m2, melw, melb, 1, flag);
  mel_kernel<<<B_ * OUT_ * 2, 256, 0, stream>>>(m2, m1, melw, melb, 2, flag);
  res_kernel<<<R_ / 4, 256, 0, stream>>>(lin, m1, resw, resb, d_out, flag);
}

// Round 5
// 3139.617 us; speedup vs baseline: 1.1163x; 1.1163x over previous
//
#include <hip/hip_runtime.h>
#include <hip/hip_bf16.h>

#define B_ 32
#define S_ 512
#define IN_ 300
#define H_ 180
#define G4_ 720
#define OUT_ 60
#define R_ 16384
#define TC_ 32
#define NC_ 16

// packed-weight region word offsets (wfu = uint/float view of same region)
#define BFRAG_O 0u        // uints [4 layers][12 w][4 g][6 s][64 lane][4 wd] f16-pair Whh B-frags = 294,912
#define PW0_O   294912u   // uints [720][150] f16-pair Wih0 = 108,000
#define PWR_O   402912u   // uints [3][720][90] f16-pair WihR = 194,400
#define BIASF_O 597312u   // fp32 [4][720] (bih+bhh) = 2,880
#define LINWF_O 600192u   // fp32 [60][180] = 10,800
#define LINBF_O 610992u   // fp32 [60]
#define WFT_    611052u

// ws float offsets (total 9,530,605 fl = 38.1 MB; ws >= 40 MB measured)
#define XG_O   0u         // [4 layers][2 ring] fragment-layout xg = 8 x 786,432
#define HR_O   6291456u   // [3 layers][2 ring][1024][180] fp32 = 1,105,920
#define H3_O   7397376u   // bf16 [16384][180] = 1,474,560 fl
#define WFU_O  8871936u   // 611,052 fl
#define STH_O  9482988u   // [4][32][180] h state
#define STC_O  9506028u   // [4][2 half][12 w][64 lane] float4 c state = 24,576
#define FLAG_O 9530604u
#define XGSLOT 786432
#define HRSLOT 184320

#if defined(__has_builtin)
#if __has_builtin(__builtin_amdgcn_fdot2)
#define HAVE_FDOT2 1
#endif
#endif

typedef _Float16 f16x2 __attribute__((ext_vector_type(2)));
typedef _Float16 f16x8 __attribute__((ext_vector_type(8)));
typedef float f32x4 __attribute__((ext_vector_type(4)));

union U16x8 { uint4 u; f16x8 h; };

struct Plan {
  int nl; int ll[4]; int lc[4];
  int ng; int gl[4]; int gc[4];
};

__device__ __forceinline__ float sigf(float x)   { return 1.f / (1.f + __expf(-x)); }
__device__ __forceinline__ float tanhf2(float x) { return 2.f / (1.f + __expf(-2.f * x)) - 1.f; }
__device__ __forceinline__ float toF(__hip_bfloat16 x) { return __bfloat162float(x); }
__device__ __forceinline__ float ldr(const void* p, long i, int fl) {
  return fl ? ((const float*)p)[i] : toF(((const __hip_bfloat16*)p)[i]);
}
__device__ __forceinline__ unsigned f16b(_Float16 h) {
  union { _Float16 f; unsigned short s; } x; x.f = h; return x.s;
}
__device__ __forceinline__ float h2f(unsigned s) {
  union { unsigned short s; _Float16 f; } x; x.s = (unsigned short)(s & 0xFFFFu);
  return (float)x.f;
}
__device__ __forceinline__ f16x2 u2h(unsigned u) {
  union { unsigned u; f16x2 v; } x; x.u = u; return x.v;
}
__device__ __forceinline__ float fd2(unsigned hu, unsigned wu, float acc) {
#ifdef HAVE_FDOT2
  return __builtin_amdgcn_fdot2(u2h(hu), u2h(wu), acc, false);
#else
  return acc + h2f(hu) * h2f(wu) + h2f(hu >> 16) * h2f(wu >> 16);
#endif
}
__device__ __forceinline__ unsigned packpair_f32(float lo, float hi) {
  return f16b((_Float16)lo) | (f16b((_Float16)hi) << 16);
}
__device__ __forceinline__ unsigned packpair_bf16(unsigned u) {
  union { unsigned v; float f; } a, b;
  a.v = u << 16; b.v = u & 0xFFFF0000u;
  return packpair_f32(a.f, b.f);
}

// Streamed Whh B-fragments: 3 ping-pong banks (X/Y/Z) of 4 gate-frags each.
// Residency is impossible (96 words; rounds 0/2/4 all spilled) — so stream
// each group from L2 every step with load->use distance 2. WAR deps on the
// banks cap in-flight regs at 48 words; loads stay in flight across the raw
// s_barrier (no vmcnt drain). bp is laundered per-iteration to defeat LICM.
#define LDGRP(B, s) { U16x8 u0_, u1_, u2_, u3_; \
  u0_.u = bp[(0 * 6 + (s)) * 64]; u1_.u = bp[(1 * 6 + (s)) * 64]; \
  u2_.u = bp[(2 * 6 + (s)) * 64]; u3_.u = bp[(3 * 6 + (s)) * 64]; \
  B##a = u0_.h; B##b = u1_.h; B##c = u2_.h; B##d = u3_.h; }

#define MSTB(B, s) { \
  const f16x8 av = *(const f16x8*)(hbc + (li * 384 + (((q * 16) + (s) * 64) ^ ((li & 7) << 4)))); \
  a0 = __builtin_amdgcn_mfma_f32_16x16x32_f16(av, B##a, a0, 0, 0, 0); \
  a1 = __builtin_amdgcn_mfma_f32_16x16x32_f16(av, B##b, a1, 0, 0, 0); \
  a2 = __builtin_amdgcn_mfma_f32_16x16x32_f16(av, B##c, a2, 0, 0, 0); \
  a3 = __builtin_amdgcn_mfma_f32_16x16x32_f16(av, B##d, a3, 0, 0, 0); }

// ---------------------------------------------------------------------------
__global__ __launch_bounds__(256) void detect_kernel(
    const unsigned short* __restrict__ xw, int* __restrict__ flag) {
  __shared__ int cnt;
  if (threadIdx.x == 0) cnt = 0;
  __syncthreads();
  int lc = 0;
  for (int i = threadIdx.x; i < 2048; i += 256) {
    const int e = (xw[i] >> 7) & 0xFF;
    if (e >= 0xC0 || (e > 0 && e < 0x40)) lc++;
  }
  atomicAdd(&cnt, lc);
  __syncthreads();
  if (threadIdx.x == 0) *flag = (cnt > 100) ? 1 : 0;
}

// ---------------------------------------------------------------------------
// prep: Whh as MFMA B-fragments; Wih0 packed [o][150]; WihR packed [l][o][90];
// bias/linw/linb fp32.
// ---------------------------------------------------------------------------
__global__ __launch_bounds__(256) void prep_kernel(
    const void* __restrict__ wih0, const void* __restrict__ wihr,
    const void* __restrict__ whh,  const void* __restrict__ bih,
    const void* __restrict__ bhh,  const void* __restrict__ linw,
    const void* __restrict__ linb, float* __restrict__ wf,
    const int* __restrict__ flag) {
  const unsigned i = blockIdx.x * 256u + threadIdx.x;
  if (i >= WFT_) return;
  const int fl = *flag;
  if (i < PW0_O) {            // Whh B-fragments: word = [l][w][g][s][lane][wd]
    const unsigned l = i / 73728u, idx = i % 73728u;
    const unsigned wd = idx & 3u, lane = (idx >> 2) & 63u;
    const unsigned rest = idx >> 8;
    const unsigned s = rest % 6u, gq = rest / 6u;
    const unsigned g = gq & 3u, wv = gq >> 2;
    const unsigned k0 = s * 32u + ((lane >> 4) << 3) + wd * 2u;  // k index (pair base)
    const unsigned uu = wv * 16u + (lane & 15u);                 // unit (col)
    float v0 = 0.f, v1 = 0.f;
    if (uu < 180u) {
      const long b = (long)l * 129600 + (long)(g * 180u + uu) * H_;
      if (k0 < 180u)      v0 = ldr(whh, b + k0, fl);
      if (k0 + 1u < 180u) v1 = ldr(whh, b + k0 + 1u, fl);
    }
    ((unsigned*)wf)[i] = packpair_f32(v0, v1);
    return;
  }
  if (i < PWR_O) {            // Wih0 [o][150] pairs
    const unsigned j = i - PW0_O, o = j / 150u, kp = j % 150u;
    const long b = (long)o * IN_;
    ((unsigned*)wf)[i] =
        packpair_f32(ldr(wih0, b + 2 * kp, fl), ldr(wih0, b + 2 * kp + 1, fl));
    return;
  }
  if (i < BIASF_O) {          // WihR [l][o][90] pairs
    const unsigned j = i - PWR_O, l = j / 64800u, r = j % 64800u;
    const unsigned o = r / 90u, kp = r % 90u;
    const long b = (long)l * 129600 + (long)o * H_;
    ((unsigned*)wf)[i] =
        packpair_f32(ldr(wihr, b + 2 * kp, fl), ldr(wihr, b + 2 * kp + 1, fl));
    return;
  }
  float v;
  if (i < LINWF_O)      { const unsigned j = i - BIASF_O; v = ldr(bih, j, fl) + ldr(bhh, j, fl); }
  else if (i < LINBF_O) v = ldr(linw, i - LINWF_O, fl);
  else                  v = ldr(linb, i - LINBF_O, fl);
  wf[i] = v;
}

// ---------------------------------------------------------------------------
// fused: blocks [0, nl*2) = LSTM jobs (MFMA recurrence, 16 batches/block,
// 12 waves: wave w owns units [16w,16w+16) x all 4 gates -> in-lane c/h update,
// one raw barrier per step, streamed weights); rest = barrier GEMM (f16 dot2,
// proven tiling) writing xg in MFMA C-fragment layout.
// ---------------------------------------------------------------------------
__global__ __launch_bounds__(768, 3) void fused_kernel(
    const void* __restrict__ x, const int* __restrict__ flag,
    const unsigned* __restrict__ wfu,
    float* __restrict__ xg, float* __restrict__ hr,
    __hip_bfloat16* __restrict__ h3,
    float* __restrict__ sth, float* __restrict__ stc, Plan p) {
  __shared__ __align__(16) unsigned short hbf[2 * 16 * 192];   // h dbuf, XOR-swizzled
  __shared__ __align__(16) unsigned Asu[3][10][68];
  __shared__ __align__(16) unsigned Bsu[3][10][68];

  const int bid = blockIdx.x;
  if (bid < p.nl * 2) {
    // ---------------- LSTM: MFMA recurrence, streamed weights ----------------
    const int j = bid >> 1, half = bid & 1;
    const int l = p.ll[j], c = p.lc[j];
    const int tid = threadIdx.x;
    const int w = tid >> 6, lane = tid & 63;
    const int li = lane & 15, q = lane >> 4;
    const int u = w * 16 + li;                       // unit (0..191, pad >=180)
    const uint4* bfp = (const uint4*)(wfu + BFRAG_O) +
                       ((long)l * 18432 + w * 1536 + lane);
    f32x4* stc4 = (f32x4*)stc;
    const int sidx = ((l * 2 + half) * 12 + w) * 64 + lane;
    f32x4 cr = {0.f, 0.f, 0.f, 0.f};
    if (c != 0) cr = stc4[sidx];
    float* hrs = (l < 3) ? (hr + (long)(l * 2 + (c & 1)) * HRSLOT) : (float*)0;
    const f32x4* xgf = (const f32x4*)(xg + (long)(l * 2 + (c & 1)) * XGSLOT);
    const int xb = (half * 12 + w) * 256 + lane;
    // seed h buffer 0 from carried state (zeros on first chunk / pad cols)
    {
      char* hbw0 = (char*)hbf;
      for (int e = tid; e < 16 * 192; e += 768) {
        const int bb = e / 192, uu = e - bb * 192;
        float hv = 0.f;
        if (c != 0 && uu < 180) hv = sth[(l * 32 + half * 16 + bb) * 180 + uu];
        *(unsigned short*)(hbw0 + bb * 384 + ((uu * 2) ^ ((bb & 7) << 4))) =
            (unsigned short)f16b((_Float16)hv);
      }
    }
    // weight stream banks: X=G0, Y=G1 on entry of each step; Z scratch
    f16x8 Xa, Xb, Xc, Xd, Ya, Yb, Yc, Yd, Za, Zb, Zc, Zd;
    {
      const uint4* bp = bfp;
      LDGRP(X, 0)
      LDGRP(Y, 1)
    }
    f32x4 nx0 = xgf[xb], nx1 = xgf[xb + 64], nx2 = xgf[xb + 128], nx3 = xgf[xb + 192];
    __syncthreads();
#pragma unroll 1
    for (int t = 0; t < TC_; ++t) {
      const uint4* bp = bfp;
      asm volatile("" : "+v"(bp));                   // defeat LICM on weight loads
      const char* hbc = (const char*)hbf + ((t & 1) ? 6144 : 0);
      char* hbw = (char*)hbf + ((t & 1) ? 0 : 6144);
      f32x4 a0 = nx0, a1 = nx1, a2 = nx2, a3 = nx3;   // acc init = xg (bias folded)
      // ping-pong: load group s+2 while computing group s (distance-2 pipeline)
      LDGRP(Z, 2) MSTB(X, 0)
      LDGRP(X, 3) MSTB(Y, 1)
      LDGRP(Y, 4) MSTB(Z, 2)
      LDGRP(Z, 5) MSTB(X, 3)
      LDGRP(X, 0) MSTB(Y, 4)                         // X <- G0 for next step
      LDGRP(Y, 1) MSTB(Z, 5)                         // Y <- G1 for next step
      if (t + 1 < TC_) {                               // prefetch next xg fragment
        const long xi = xb + (long)(t + 1) * 6144;
        nx0 = xgf[xi]; nx1 = xgf[xi + 64]; nx2 = xgf[xi + 128]; nx3 = xgf[xi + 192];
      }
#pragma unroll
      for (int r = 0; r < 4; ++r) {
        const float ig = sigf(a0[r]), fg = sigf(a1[r]);
        const float gg = tanhf2(a2[r]), og = sigf(a3[r]);
        const float cn = fg * cr[r] + ig * gg;
        cr[r] = cn;
        float h = og * tanhf2(cn);
        if (u >= 180) h = 0.f;                         // keep pad cols clean
        const int brow = q * 4 + r;
        *(unsigned short*)(hbw + brow * 384 + ((u * 2) ^ ((brow & 7) << 4))) =
            (unsigned short)f16b((_Float16)h);
        if (u < 180) {
          const int b = half * 16 + brow;
          if (l < 3) hrs[(long)(b * TC_ + t) * H_ + u] = h;
          else       h3[((long)b * S_ + c * TC_ + t) * H_ + u] = __float2bfloat16(h);
          if (t == TC_ - 1) sth[(l * 32 + b) * H_ + u] = h;
        }
      }
      // raw barrier: LDS writes visible, global stores/prefetch stay in flight
      asm volatile("s_waitcnt lgkmcnt(0)\n\ts_barrier" ::: "memory");
    }
    stc4[sidx] = cr;
    return;
  }

  // ---------------- GEMM: f16-pair dot2, proven barrier tiling ----------
  const int gb = bid - p.nl * 2;
  const int g = threadIdx.x >> 8, t = threadIdx.x & 255;
  const int ti = gb * 3 + g;              // grid sized exactly: ti < ng*192
  const int jj = ti / 192, idx = ti % 192;
  const int rt = idx & 15, ct = idx >> 4;
  const int l = p.gl[jj], c = p.gc[jj];
  const int fl = *flag;
  const int KP = (l == 0) ? 150 : 90;     // k-pairs
  const unsigned* Wp = (l == 0) ? (wfu + PW0_O)
                                : (wfu + PWR_O + (unsigned)(l - 1) * 64800u);
  const float* bias = (const float*)wfu + BIASF_O + (unsigned)l * G4_;
  const float* hA = (l == 0) ? (const float*)0
                  : hr + (long)((l - 1) * 2 + (c & 1)) * HRSLOT;
  float* dst = xg + (long)(l * 2 + (c & 1)) * XGSLOT;
  const int rho0 = rt * 64, o0 = ct * 64;
  const int tx = t & 15, ty = t >> 4;
  float acc[4][4] = {};
  for (int kp0 = 0; kp0 < KP; kp0 += 10) {
    for (int e = t; e < 640; e += 256) {
      const int rl = e / 10, pp = e % 10;
      const int rho = rho0 + rl;
      unsigned av;
      if (l == 0) {
        const int bb = rho >> 5, tl = rho & 31;
        const long gr = (long)bb * S_ + c * TC_ + tl;
        if (fl == 0) av = packpair_bf16(((const unsigned*)x)[gr * 150 + kp0 + pp]);
        else { const float2 f = ((const float2*)x)[gr * 150 + kp0 + pp];
               av = packpair_f32(f.x, f.y); }
      } else {
        const float2 f = ((const float2*)hA)[(long)rho * 90 + kp0 + pp];
        av = packpair_f32(f.x, f.y);
      }
      Asu[g][pp][rl] = av;
      const int o = o0 + rl;
      Bsu[g][pp][rl] = (o < G4_) ? Wp[(long)o * KP + kp0 + pp] : 0u;
    }
    __syncthreads();
#pragma unroll
    for (int pp = 0; pp < 10; ++pp) {
      const uint4 a4 = *(const uint4*)&Asu[g][pp][ty * 4];
      const uint4 b4 = *(const uint4*)&Bsu[g][pp][tx * 4];
      const unsigned av[4] = {a4.x, a4.y, a4.z, a4.w};
      const unsigned bv[4] = {b4.x, b4.y, b4.z, b4.w};
#pragma unroll
      for (int i = 0; i < 4; ++i)
#pragma unroll
        for (int j2 = 0; j2 < 4; ++j2) acc[i][j2] = fd2(av[i], bv[j2], acc[i][j2]);
    }
    __syncthreads();
  }
  // epilogue: write xg in LSTM MFMA C-fragment layout
  int oidx[4], ocol[4];
#pragma unroll
  for (int j2 = 0; j2 < 4; ++j2) {
    const int o = o0 + tx * 4 + j2;
    ocol[j2] = o;
    if (o < G4_) {
      const int gi = o / 180, uu = o - gi * 180;
      oidx[j2] = (uu >> 4) * 1024 + gi * 256 + (uu & 15) * 4;
    } else oidx[j2] = -1;
  }
#pragma unroll
  for (int i = 0; i < 4; ++i) {
    const int rho = rho0 + ty * 4 + i;
    const int bb = rho >> 5, tt = rho & 31;
    const int hf = bb >> 4, bt = bb & 15;
    const long rowoff = (long)(tt * 2 + hf) * 12288 + (bt >> 2) * 64 + (bt & 3);
#pragma unroll
    for (int j2 = 0; j2 < 4; ++j2)
      if (oidx[j2] >= 0) dst[rowoff + oidx[j2]] = acc[i][j2] + bias[ocol[j2]];
  }
}

// ---------------------------------------------------------------------------
// linear as tiled GEMM: [16384 x 180] @ [180 x 60] -> out[b][c][s].
// ---------------------------------------------------------------------------
__global__ __launch_bounds__(256) void linear_kernel(
    const __hip_bfloat16* __restrict__ h, const float* __restrict__ linw,
    const float* __restrict__ linb, float* __restrict__ out) {
  __shared__ __align__(16) float Ast[20][68];
  __shared__ __align__(16) float Bst[20][68];
  const int bt = blockIdx.x;
  const int b = bt >> 3, st0 = (bt & 7) * 64;
  const int t = threadIdx.x, tx = t & 15, ty = t >> 4;
  float acc[4][4] = {};
  for (int k0 = 0; k0 < H_; k0 += 20) {
    for (int e = t; e < 1280; e += 256) {
      const int rl = e / 20, kk = e % 20;
      Ast[kk][rl] = toF(h[(long)(b * S_ + st0 + rl) * H_ + k0 + kk]);
      Bst[kk][rl] = (rl < OUT_) ? linw[rl * H_ + k0 + kk] : 0.f;
    }
    __syncthreads();
#pragma unroll
    for (int kk = 0; kk < 20; ++kk) {
      const float4 a4 = *(const float4*)&Ast[kk][ty * 4];
      const float4 b4 = *(const float4*)&Bst[kk][tx * 4];
      const float av[4] = {a4.x, a4.y, a4.z, a4.w};
      const float bv[4] = {b4.x, b4.y, b4.z, b4.w};
#pragma unroll
      for (int i = 0; i < 4; ++i)
#pragma unroll
        for (int j2 = 0; j2 < 4; ++j2) acc[i][j2] += av[i] * bv[j2];
    }
    __syncthreads();
  }
#pragma unroll
  for (int i = 0; i < 4; ++i) {
    const int s = st0 + ty * 4 + i;
#pragma unroll
    for (int j2 = 0; j2 < 4; ++j2) {
      const int c = tx * 4 + j2;
      if (c < OUT_) out[((long)b * OUT_ + c) * S_ + s] = acc[i][j2] + linb[c];
    }
  }
}

// ---------------------------------------------------------------------------
__global__ __launch_bounds__(256) void mel_kernel(
    const float* __restrict__ in, float* __restrict__ out,
    const void* __restrict__ mw, const void* __restrict__ mb,
    int l, const int* __restrict__ flag) {
  const int fl = *flag;
  const int idx = blockIdx.x;
  const int s = (idx & 1) * 256 + threadIdx.x;
  const int c = (idx >> 1) % OUT_;
  const int b = idx / (2 * OUT_);
  const int j = c % 3, i = c / 3;
  float acc = ldr(mb, (l * 3 + j) * 20 + i, fl);
  const long wbase = (long)((l * 3 + j) * 20 + i) * 15;
#pragma unroll
  for (int q = 0; q < 3; ++q) {
    const int ch = 3 * i + q + j - 1;
    if (ch < 0 || ch >= OUT_) continue;
    const float* xr = in + ((long)b * OUT_ + ch) * S_;
#pragma unroll
    for (int k = 0; k < 5; ++k) {
      const int sp = s + k - 2;
      if (sp < 0 || sp >= S_) continue;
      acc += ldr(mw, wbase + q * 5 + k, fl) * xr[sp];
    }
  }
  out[((long)b * OUT_ + c) * S_ + s] = acc + in[((long)b * OUT_ + c) * S_ + s];
}

// ---------------------------------------------------------------------------
__global__ __launch_bounds__(256) void res_kernel(
    const float* __restrict__ lin, const float* __restrict__ mel,
    const void* __restrict__ rw, const void* __restrict__ rb,
    void* __restrict__ outp, const int* __restrict__ flag) {
  const int fl = *flag;
  const int q = threadIdx.x >> 6, lane = threadIdx.x & 63;
  const int bs = blockIdx.x * 4 + q;
  const int b = bs / S_, s = bs % S_;
  if (lane >= OUT_) return;
  const int c = lane;
  float acc = ldr(rb, c, fl);
  const float* x0 = lin + ((long)b * OUT_ + c) * S_;
  const float* x1 = mel + ((long)b * OUT_ + c) * S_;
#pragma unroll
  for (int k = 0; k < 5; ++k) {
    const int sp = s + k - 2;
    if (sp < 0 || sp >= S_) continue;
    acc += ldr(rw, c * 10 + k, fl) * x0[sp] + ldr(rw, c * 10 + 5 + k, fl) * x1[sp];
  }
  const long oi = (long)bs * OUT_ + c;
  if (fl == 0) ((__hip_bfloat16*)outp)[oi] = __float2bfloat16(acc);
  else ((float*)outp)[oi] = acc;
}

// ---------------------------------------------------------------------------
extern "C" void kernel_launch(void* const* d_in, const int* in_sizes, int n_in,
                              void* d_out, int out_size, void* d_ws, size_t ws_size,
                              hipStream_t stream) {
  const void* x    = d_in[0];
  const void* wih0 = d_in[1];
  const void* wihr = d_in[2];
  const void* whh  = d_in[3];
  const void* bih  = d_in[4];
  const void* bhh  = d_in[5];
  const void* linw = d_in[6];
  const void* linb = d_in[7];
  const void* melw = d_in[8];
  const void* melb = d_in[9];
  const void* resw = d_in[10];
  const void* resb = d_in[11];

  float* ws = (float*)d_ws;
  float* xg = ws + XG_O;
  float* hrp = ws + HR_O;
  __hip_bfloat16* h3 = (__hip_bfloat16*)(ws + H3_O);
  float* wf = ws + WFU_O;
  const unsigned* wfu = (const unsigned*)wf;
  float* sth = ws + STH_O;
  float* stc = ws + STC_O;
  int* flag = (int*)(ws + FLAG_O);
  float* lin = ws + XG_O;            // epilogue aliases dead xg region
  float* m1 = lin + 983040;
  float* m2 = m1 + 983040;

  detect_kernel<<<1, 256, 0, stream>>>((const unsigned short*)x, flag);
  prep_kernel<<<(WFT_ + 255) / 256, 256, 0, stream>>>(
      wih0, wihr, whh, bih, bhh, linw, linb, wf, flag);

  // prologue: gemm(0,0) only
  {
    Plan p = {};
    p.nl = 0; p.ng = 1; p.gl[0] = 0; p.gc[0] = 0;
    fused_kernel<<<64, 768, 0, stream>>>(x, flag, wfu, xg, hrp, h3, sth, stc, p);
  }
  // pipeline: lstm(l,c) at launch n = c + 2l; gemm(l,c) at n = c + 2l - 1
  for (int n = 0; n <= 21; ++n) {
    Plan p = {};
    for (int l = 0; l < 4; ++l) {
      const int c = n - 2 * l;
      if (c >= 0 && c < NC_) { p.ll[p.nl] = l; p.lc[p.nl] = c; p.nl++; }
    }
    for (int l = 0; l < 4; ++l) {
      const int c = n + 1 - 2 * l;
      if (c >= 0 && c < NC_) { p.gl[p.ng] = l; p.gc[p.ng] = c; p.ng++; }
    }
    const int grid = p.nl * 2 + p.ng * 64;
    fused_kernel<<<grid, 768, 0, stream>>>(x, flag, wfu, xg, hrp, h3, sth, stc, p);
  }

  linear_kernel<<<256, 256, 0, stream>>>(h3, wf + LINWF_O, wf + LINBF_O, lin);
  mel_kernel<<<B_ * OUT_ * 2, 256, 0, stream>>>(lin, m1, melw, melb, 0, flag);
  mel_kernel<<<B_ * OUT_ * 2, 256, 0, stream>>>(m1, m2, melw, melb, 1, flag);
  mel_kernel<<<B_ * OUT_ * 2, 256, 0, stream>>>(m2, m1, melw, melb, 2, flag);
  res_kernel<<<R_ / 4, 256, 0, stream>>>(lin, m1, resw, resb, d_out, flag);
}

// Round 6
// 1512.335 us; speedup vs baseline: 2.3174x; 2.0760x over previous
//
#include <hip/hip_runtime.h>
#include <hip/hip_bf16.h>

#define B_ 32
#define S_ 512
#define IN_ 300
#define H_ 180
#define G4_ 720
#define OUT_ 60
#define R_ 16384
#define TC_ 32
#define NC_ 16
#define NPK_ 92

// packed-weight region word offsets (wfu = uint/float view of same region)
#define PWHH_O  0u        // uints [4][92][720] f16-pair Whh^T = 264,960
#define PW0_O   264960u   // uints [720][150] f16-pair Wih0 = 108,000
#define PWR_O   372960u   // uints [3][720][90] f16-pair WihR = 194,400
#define BIASF_O 567360u   // fp32 [4][720] (bih+bhh) = 2,880
#define LINWF_O 570240u   // fp32 [60][180] = 10,800
#define LINBF_O 581040u   // fp32 [60]
#define WFT_    581100u

// ws float offsets (total 9,105,901 fl = 36.4 MB; ws >= 40 MB measured)
#define XG_O   0u         // [4 layers][2 ring][1024][720] fp32 = 5,898,240
#define HR_O   5898240u   // [3 layers][2 ring][1024][180] fp32 = 1,105,920
#define H3_O   7004160u   // bf16 [16384][180] = 1,474,560 fl
#define WFU_O  8478720u   // 581,100 fl
#define STH_O  9059820u   // [4][32][180]
#define STC_O  9082860u
#define FLAG_O 9105900u
#define XGSLOT 737280
#define HRSLOT 184320

#if defined(__has_builtin)
#if __has_builtin(__builtin_amdgcn_fdot2)
#define HAVE_FDOT2 1
#endif
#endif

typedef _Float16 f16x2 __attribute__((ext_vector_type(2)));

struct Plan {
  int nl; int ll[4]; int lc[4];
  int ng; int gl[4]; int gc[4];
};

__device__ __forceinline__ float sigf(float x)   { return 1.f / (1.f + __expf(-x)); }
__device__ __forceinline__ float tanhf2(float x) { return 2.f / (1.f + __expf(-2.f * x)) - 1.f; }
__device__ __forceinline__ float toF(__hip_bfloat16 x) { return __bfloat162float(x); }
__device__ __forceinline__ float ldr(const void* p, long i, int fl) {
  return fl ? ((const float*)p)[i] : toF(((const __hip_bfloat16*)p)[i]);
}
__device__ __forceinline__ unsigned f16b(_Float16 h) {
  union { _Float16 f; unsigned short s; } x; x.f = h; return x.s;
}
__device__ __forceinline__ float h2f(unsigned s) {
  union { unsigned short s; _Float16 f; } x; x.s = (unsigned short)(s & 0xFFFFu);
  return (float)x.f;
}
__device__ __forceinline__ f16x2 u2h(unsigned u) {
  union { unsigned u; f16x2 v; } x; x.u = u; return x.v;
}
__device__ __forceinline__ float fd2(unsigned hu, unsigned wu, float acc) {
#ifdef HAVE_FDOT2
  return __builtin_amdgcn_fdot2(u2h(hu), u2h(wu), acc, false);
#else
  return acc + h2f(hu) * h2f(wu) + h2f(hu >> 16) * h2f(wu >> 16);
#endif
}
__device__ __forceinline__ unsigned packpair_f32(float lo, float hi) {
  return f16b((_Float16)lo) | (f16b((_Float16)hi) << 16);
}
__device__ __forceinline__ unsigned packpair_bf16(unsigned u) {
  union { unsigned v; float f; } a, b;
  a.v = u << 16; b.v = u & 0xFFFF0000u;
  return packpair_f32(a.f, b.f);
}

// 23 groups x 4 Whh pair-words = 92 named scalars (SROA-proof, asm-pinned)
#define REP23(M) M(0) M(1) M(2) M(3) M(4) M(5) M(6) M(7) M(8) M(9) M(10) \
  M(11) M(12) M(13) M(14) M(15) M(16) M(17) M(18) M(19) M(20) M(21) M(22)
#define LW(n) \
  unsigned w##n##a = wp0[(4*n+0)*G4_], w##n##b = wp0[(4*n+1)*G4_], \
           w##n##c = wp0[(4*n+2)*G4_], w##n##d = wp0[(4*n+3)*G4_];
#define PW(n) \
  asm volatile("" : "+v"(w##n##a), "+v"(w##n##b), "+v"(w##n##c), "+v"(w##n##d));
#define ST(n) { \
  const uint4 hh = *(const uint4*)&hpk[4*n]; \
  a0 = fd2(hh.x, w##n##a, a0); a1 = fd2(hh.y, w##n##b, a1); \
  a2 = fd2(hh.z, w##n##c, a2); a3 = fd2(hh.w, w##n##d, a3); }

// ---------------------------------------------------------------------------
__global__ __launch_bounds__(256) void detect_kernel(
    const unsigned short* __restrict__ xw, int* __restrict__ flag) {
  __shared__ int cnt;
  if (threadIdx.x == 0) cnt = 0;
  __syncthreads();
  int lc = 0;
  for (int i = threadIdx.x; i < 2048; i += 256) {
    const int e = (xw[i] >> 7) & 0xFF;
    if (e >= 0xC0 || (e > 0 && e < 0x40)) lc++;
  }
  atomicAdd(&cnt, lc);
  __syncthreads();
  if (threadIdx.x == 0) *flag = (cnt > 100) ? 1 : 0;
}

// ---------------------------------------------------------------------------
// prep: Whh packed [l][jp][o]; Wih0 packed [o][150]; WihR packed [l][o][90];
// bias/linw/linb fp32.
// ---------------------------------------------------------------------------
__global__ __launch_bounds__(256) void prep_kernel(
    const void* __restrict__ wih0, const void* __restrict__ wihr,
    const void* __restrict__ whh,  const void* __restrict__ bih,
    const void* __restrict__ bhh,  const void* __restrict__ linw,
    const void* __restrict__ linb, float* __restrict__ wf,
    const int* __restrict__ flag) {
  const unsigned i = blockIdx.x * 256u + threadIdx.x;
  if (i >= WFT_) return;
  const int fl = *flag;
  if (i < PW0_O) {            // Whh packed transposed
    const unsigned l = i / 66240u, r = i % 66240u;
    const unsigned jp = r / 720u, o = r % 720u;
    unsigned u = 0u;
    if (jp < 90u) {
      const long b = (long)l * 129600 + (long)o * H_;
      u = packpair_f32(ldr(whh, b + 2 * jp, fl), ldr(whh, b + 2 * jp + 1, fl));
    }
    ((unsigned*)wf)[i] = u;
    return;
  }
  if (i < PWR_O) {            // Wih0 [o][150] pairs
    const unsigned j = i - PW0_O, o = j / 150u, kp = j % 150u;
    const long b = (long)o * IN_;
    ((unsigned*)wf)[i] =
        packpair_f32(ldr(wih0, b + 2 * kp, fl), ldr(wih0, b + 2 * kp + 1, fl));
    return;
  }
  if (i < BIASF_O) {          // WihR [l][o][90] pairs
    const unsigned j = i - PWR_O, l = j / 64800u, r = j % 64800u;
    const unsigned o = r / 90u, kp = r % 90u;
    const long b = (long)l * 129600 + (long)o * H_;
    ((unsigned*)wf)[i] =
        packpair_f32(ldr(wihr, b + 2 * kp, fl), ldr(wihr, b + 2 * kp + 1, fl));
    return;
  }
  float v;
  if (i < LINWF_O)      { const unsigned j = i - BIASF_O; v = ldr(bih, j, fl) + ldr(bhh, j, fl); }
  else if (i < LINBF_O) v = ldr(linw, i - LINWF_O, fl);
  else                  v = ldr(linb, i - LINBF_O, fl);
  wf[i] = v;
}

// ---------------------------------------------------------------------------
// fused: blocks [0, nl*32) = LSTM jobs; rest = barrier GEMM, f16-pair dot2,
// 3x 64x64 tiles per 768-block (proven tiling/barrier skeleton).
// LSTM in-loop barriers are raw lgkmcnt(0)+s_barrier (T4): per-step global
// stores (hrs/h3/sth) and the xcur prefetch stay in flight across the
// barrier instead of being drained by __syncthreads' vmcnt(0).
// ---------------------------------------------------------------------------
__global__ __launch_bounds__(768, 3) void fused_kernel(
    const void* __restrict__ x, const int* __restrict__ flag,
    const unsigned* __restrict__ wfu,
    float* __restrict__ xg, float* __restrict__ hr,
    __hip_bfloat16* __restrict__ h3,
    float* __restrict__ sth, float* __restrict__ stc, Plan p) {
  __shared__ __align__(16) unsigned hpk[NPK_];
  __shared__ float gbuf[G4_];
  __shared__ __align__(16) unsigned Asu[3][10][68];
  __shared__ __align__(16) unsigned Bsu[3][10][68];

  const int bid = blockIdx.x;
  if (bid < p.nl * 32) {
    // ---------------- LSTM (r0 proven body, raw in-loop barriers) ----------
    const int j = bid >> 5, b = bid & 31;
    const int l = p.ll[j], c = p.lc[j];
    const int o = threadIdx.x;
    const bool act = o < G4_;
    const int oc = act ? o : 0;
    const unsigned* wp0 = wfu + PWHH_O + (unsigned)l * (NPK_ * G4_) + oc;
    REP23(LW)
    REP23(PW)
    const float* xgs = xg + (long)(l * 2 + (c & 1)) * XGSLOT;
    float* hrs = hr + (long)((l < 3 ? l : 0) * 2 + (c & 1)) * HRSLOT;
    float cst = 0.f;
    if (o == 180 || o == 181) hpk[o - 90] = 0u;
    if (o < H_) {
      float h = 0.f;
      if (c != 0) { h = sth[(l * 32 + b) * H_ + o]; cst = stc[(l * 32 + b) * H_ + o]; }
      const unsigned v = f16b((_Float16)h);
      const unsigned nx = __shfl_down(v, 1);
      if ((o & 1) == 0) hpk[o >> 1] = v | (nx << 16);
    }
    const float* xgp = xgs + (long)b * TC_ * G4_ + oc;
    float xcur = xgp[0];
    __syncthreads();
    for (int tl = 0; tl < TC_; ++tl) {
      {
        float a0 = xcur, a1 = 0.f, a2 = 0.f, a3 = 0.f;
        REP23(ST)
        const float acc = (a0 + a1) + (a2 + a3);
        const bool isg = (o >= 2 * H_) && (o < 3 * H_);
        if (act) gbuf[o] = isg ? tanhf2(acc) : sigf(acc);
        const int tn = (tl + 1 < TC_) ? tl + 1 : tl;
        xcur = xgp[(long)tn * G4_];
      }
      // raw barrier: gbuf (LDS) visible; global stores/prefetch not drained
      asm volatile("s_waitcnt lgkmcnt(0)\n\ts_barrier" ::: "memory");
      if (o < H_) {
        cst = gbuf[H_ + o] * cst + gbuf[o] * gbuf[2 * H_ + o];
        const float h = gbuf[3 * H_ + o] * tanhf2(cst);
        if (l < 3) hrs[(b * TC_ + tl) * H_ + o] = h;
        else h3[((long)b * S_ + c * TC_ + tl) * H_ + o] = __float2bfloat16(h);
        const unsigned v = f16b((_Float16)h);
        const unsigned nx = __shfl_down(v, 1);
        if ((o & 1) == 0) hpk[o >> 1] = v | (nx << 16);
        if (tl == TC_ - 1) {
          sth[(l * 32 + b) * H_ + o] = h; stc[(l * 32 + b) * H_ + o] = cst;
        }
      }
      // raw barrier: hpk (LDS) visible for next step's ST reads
      asm volatile("s_waitcnt lgkmcnt(0)\n\ts_barrier" ::: "memory");
    }
    return;
  }

  // ---------------- GEMM: f16-pair dot2, proven barrier tiling ----------
  const int gb = bid - p.nl * 32;
  const int g = threadIdx.x >> 8, t = threadIdx.x & 255;
  const int ti = gb * 3 + g;              // grid sized exactly: ti < ng*192
  const int jj = ti / 192, idx = ti % 192;
  const int rt = idx & 15, ct = idx >> 4;
  const int l = p.gl[jj], c = p.gc[jj];
  const int fl = *flag;
  const int KP = (l == 0) ? 150 : 90;     // k-pairs
  const unsigned* Wp = (l == 0) ? (wfu + PW0_O)
                                : (wfu + PWR_O + (unsigned)(l - 1) * 64800u);
  const float* bias = (const float*)wfu + BIASF_O + (unsigned)l * G4_;
  const float* hA = (l == 0) ? nullptr
                  : hr + (long)((l - 1) * 2 + (c & 1)) * HRSLOT;
  float* dst = xg + (long)(l * 2 + (c & 1)) * XGSLOT;
  const int rho0 = rt * 64, o0 = ct * 64;
  const int tx = t & 15, ty = t >> 4;
  float acc[4][4] = {};
  for (int kp0 = 0; kp0 < KP; kp0 += 10) {
    for (int e = t; e < 640; e += 256) {
      const int rl = e / 10, pp = e % 10;
      const int rho = rho0 + rl;
      unsigned av;
      if (l == 0) {
        const int bb = rho >> 5, tl = rho & 31;
        const long gr = (long)bb * S_ + c * TC_ + tl;
        if (fl == 0) av = packpair_bf16(((const unsigned*)x)[gr * 150 + kp0 + pp]);
        else { const float2 f = ((const float2*)x)[gr * 150 + kp0 + pp];
               av = packpair_f32(f.x, f.y); }
      } else {
        const float2 f = ((const float2*)hA)[(long)rho * 90 + kp0 + pp];
        av = packpair_f32(f.x, f.y);
      }
      Asu[g][pp][rl] = av;
      const int o = o0 + rl;
      Bsu[g][pp][rl] = (o < G4_) ? Wp[(long)o * KP + kp0 + pp] : 0u;
    }
    __syncthreads();
#pragma unroll
    for (int pp = 0; pp < 10; ++pp) {
      const uint4 a4 = *(const uint4*)&Asu[g][pp][ty * 4];
      const uint4 b4 = *(const uint4*)&Bsu[g][pp][tx * 4];
      const unsigned av[4] = {a4.x, a4.y, a4.z, a4.w};
      const unsigned bv[4] = {b4.x, b4.y, b4.z, b4.w};
#pragma unroll
      for (int i = 0; i < 4; ++i)
#pragma unroll
        for (int j2 = 0; j2 < 4; ++j2) acc[i][j2] = fd2(av[i], bv[j2], acc[i][j2]);
    }
    __syncthreads();
  }
#pragma unroll
  for (int i = 0; i < 4; ++i) {
    const int rho = rho0 + ty * 4 + i;
#pragma unroll
    for (int j2 = 0; j2 < 4; ++j2) {
      const int o = o0 + tx * 4 + j2;
      if (o < G4_) dst[(long)rho * G4_ + o] = acc[i][j2] + bias[o];
    }
  }
}

// ---------------------------------------------------------------------------
// linear as tiled GEMM: [16384 x 180] @ [180 x 60] -> out[b][c][s].
// ---------------------------------------------------------------------------
__global__ __launch_bounds__(256) void linear_kernel(
    const __hip_bfloat16* __restrict__ h, const float* __restrict__ linw,
    const float* __restrict__ linb, float* __restrict__ out) {
  __shared__ __align__(16) float Ast[20][68];
  __shared__ __align__(16) float Bst[20][68];
  const int bt = blockIdx.x;
  const int b = bt >> 3, st0 = (bt & 7) * 64;
  const int t = threadIdx.x, tx = t & 15, ty = t >> 4;
  float acc[4][4] = {};
  for (int k0 = 0; k0 < H_; k0 += 20) {
    for (int e = t; e < 1280; e += 256) {
      const int rl = e / 20, kk = e % 20;
      Ast[kk][rl] = toF(h[(long)(b * S_ + st0 + rl) * H_ + k0 + kk]);
      Bst[kk][rl] = (rl < OUT_) ? linw[rl * H_ + k0 + kk] : 0.f;
    }
    __syncthreads();
#pragma unroll
    for (int kk = 0; kk < 20; ++kk) {
      const float4 a4 = *(const float4*)&Ast[kk][ty * 4];
      const float4 b4 = *(const float4*)&Bst[kk][tx * 4];
      const float av[4] = {a4.x, a4.y, a4.z, a4.w};
      const float bv[4] = {b4.x, b4.y, b4.z, b4.w};
#pragma unroll
      for (int i = 0; i < 4; ++i)
#pragma unroll
        for (int j2 = 0; j2 < 4; ++j2) acc[i][j2] += av[i] * bv[j2];
    }
    __syncthreads();
  }
#pragma unroll
  for (int i = 0; i < 4; ++i) {
    const int s = st0 + ty * 4 + i;
#pragma unroll
    for (int j2 = 0; j2 < 4; ++j2) {
      const int c = tx * 4 + j2;
      if (c < OUT_) out[((long)b * OUT_ + c) * S_ + s] = acc[i][j2] + linb[c];
    }
  }
}

// ---------------------------------------------------------------------------
__global__ __launch_bounds__(256) void mel_kernel(
    const float* __restrict__ in, float* __restrict__ out,
    const void* __restrict__ mw, const void* __restrict__ mb,
    int l, const int* __restrict__ flag) {
  const int fl = *flag;
  const int idx = blockIdx.x;
  const int s = (idx & 1) * 256 + threadIdx.x;
  const int c = (idx >> 1) % OUT_;
  const int b = idx / (2 * OUT_);
  const int j = c % 3, i = c / 3;
  float acc = ldr(mb, (l * 3 + j) * 20 + i, fl);
  const long wbase = (long)((l * 3 + j) * 20 + i) * 15;
#pragma unroll
  for (int q = 0; q < 3; ++q) {
    const int ch = 3 * i + q + j - 1;
    if (ch < 0 || ch >= OUT_) continue;
    const float* xr = in + ((long)b * OUT_ + ch) * S_;
#pragma unroll
    for (int k = 0; k < 5; ++k) {
      const int sp = s + k - 2;
      if (sp < 0 || sp >= S_) continue;
      acc += ldr(mw, wbase + q * 5 + k, fl) * xr[sp];
    }
  }
  out[((long)b * OUT_ + c) * S_ + s] = acc + in[((long)b * OUT_ + c) * S_ + s];
}

// ---------------------------------------------------------------------------
__global__ __launch_bounds__(256) void res_kernel(
    const float* __restrict__ lin, const float* __restrict__ mel,
    const void* __restrict__ rw, const void* __restrict__ rb,
    void* __restrict__ outp, const int* __restrict__ flag) {
  const int fl = *flag;
  const int q = threadIdx.x >> 6, lane = threadIdx.x & 63;
  const int bs = blockIdx.x * 4 + q;
  const int b = bs / S_, s = bs % S_;
  if (lane >= OUT_) return;
  const int c = lane;
  float acc = ldr(rb, c, fl);
  const float* x0 = lin + ((long)b * OUT_ + c) * S_;
  const float* x1 = mel + ((long)b * OUT_ + c) * S_;
#pragma unroll
  for (int k = 0; k < 5; ++k) {
    const int sp = s + k - 2;
    if (sp < 0 || sp >= S_) continue;
    acc += ldr(rw, c * 10 + k, fl) * x0[sp] + ldr(rw, c * 10 + 5 + k, fl) * x1[sp];
  }
  const long oi = (long)bs * OUT_ + c;
  if (fl == 0) ((__hip_bfloat16*)outp)[oi] = __float2bfloat16(acc);
  else ((float*)outp)[oi] = acc;
}

// ---------------------------------------------------------------------------
extern "C" void kernel_launch(void* const* d_in, const int* in_sizes, int n_in,
                              void* d_out, int out_size, void* d_ws, size_t ws_size,
                              hipStream_t stream) {
  const void* x    = d_in[0];
  const void* wih0 = d_in[1];
  const void* wihr = d_in[2];
  const void* whh  = d_in[3];
  const void* bih  = d_in[4];
  const void* bhh  = d_in[5];
  const void* linw = d_in[6];
  const void* linb = d_in[7];
  const void* melw = d_in[8];
  const void* melb = d_in[9];
  const void* resw = d_in[10];
  const void* resb = d_in[11];

  float* ws = (float*)d_ws;
  float* xg = ws + XG_O;
  float* hrp = ws + HR_O;
  __hip_bfloat16* h3 = (__hip_bfloat16*)(ws + H3_O);
  float* wf = ws + WFU_O;
  const unsigned* wfu = (const unsigned*)wf;
  float* sth = ws + STH_O;
  float* stc = ws + STC_O;
  int* flag = (int*)(ws + FLAG_O);
  float* lin = ws + XG_O;            // epilogue aliases dead xg region
  float* m1 = lin + 983040;
  float* m2 = m1 + 983040;

  detect_kernel<<<1, 256, 0, stream>>>((const unsigned short*)x, flag);
  prep_kernel<<<(WFT_ + 255) / 256, 256, 0, stream>>>(
      wih0, wihr, whh, bih, bhh, linw, linb, wf, flag);

  // prologue: gemm(0,0) only
  {
    Plan p = {};
    p.nl = 0; p.ng = 1; p.gl[0] = 0; p.gc[0] = 0;
    fused_kernel<<<64, 768, 0, stream>>>(x, flag, wfu, xg, hrp, h3, sth, stc, p);
  }
  // pipeline: lstm(l,c) at launch n = c + 2l; gemm(l,c) at n = c + 2l - 1
  for (int n = 0; n <= 21; ++n) {
    Plan p = {};
    for (int l = 0; l < 4; ++l) {
      const int c = n - 2 * l;
      if (c >= 0 && c < NC_) { p.ll[p.nl] = l; p.lc[p.nl] = c; p.nl++; }
    }
    for (int l = 0; l < 4; ++l) {
      const int c = n + 1 - 2 * l;
      if (c >= 0 && c < NC_) { p.gl[p.ng] = l; p.gc[p.ng] = c; p.ng++; }
    }
    const int grid = p.nl * 32 + p.ng * 64;
    fused_kernel<<<grid, 768, 0, stream>>>(x, flag, wfu, xg, hrp, h3, sth, stc, p);
  }

  linear_kernel<<<256, 256, 0, stream>>>(h3, wf + LINWF_O, wf + LINBF_O, lin);
  mel_kernel<<<B_ * OUT_ * 2, 256, 0, stream>>>(lin, m1, melw, melb, 0, flag);
  mel_kernel<<<B_ * OUT_ * 2, 256, 0, stream>>>(m1, m2, melw, melb, 1, flag);
  mel_kernel<<<B_ * OUT_ * 2, 256, 0, stream>>>(m2, m1, melw, melb, 2, flag);
  res_kernel<<<R_ / 4, 256, 0, stream>>>(lin, m1, resw, resb, d_out, flag);
}